// Round 1
// baseline (5323.164 us; speedup 1.0000x reference)
//
#include <hip/hip_runtime.h>
#include <math.h>

#define GAMMA 0.5f

typedef __bf16 bf16x8 __attribute__((ext_vector_type(8)));
typedef float  f32x4  __attribute__((ext_vector_type(4)));

__device__ __forceinline__ unsigned short f2bf(float f){
  union { float ff; unsigned u; } x; x.ff = f;
  return (unsigned short)((x.u + 0x7fffu + ((x.u >> 16) & 1u)) >> 16);
}

__device__ __forceinline__ void gload16(const void* g, void* l){
  __builtin_amdgcn_global_load_lds((const __attribute__((address_space(1))) void*)g,
                                   (__attribute__((address_space(3))) void*)l,
                                   16, 0, 0);
}

// C = A[M,K] * B[N,K]^T  (both row-major, K contiguous). 128x128 tile, BK=32,
// 256 threads = 4 waves in 2x2, each wave 64x64 via 4x4 of 16x16x32 bf16 MFMA.
// MODE 0: embed  -> F0[idx]=v; F1[idx]=v           (x_emb and h init)
// MODE 1: ffn1   -> U0[idx]=bf16(tanh(v))          (activation, bf16)
// MODE 2: ffn2   -> F0[idx]=0.5*F0+0.5*(v+R0[idx]) (h update in place)
// MODE 3: head   -> if(n<nmax) F0[idx]=v           (bounded N store)
template<int MODE>
__global__ __launch_bounds__(256)
void gemm_bt(const unsigned short* __restrict__ A,
             const unsigned short* __restrict__ B,
             int K, const float* __restrict__ bias,
             int ldc, int nmax,
             float* __restrict__ F0, float* __restrict__ F1,
             unsigned short* __restrict__ U0,
             const float* __restrict__ R0)
{
  const int m0 = blockIdx.y * 128, n0 = blockIdx.x * 128;
  const int t = threadIdx.x, w = t >> 6, l = t & 63;
  __shared__ __align__(16) unsigned short lgA[128 * 32];
  __shared__ __align__(16) unsigned short lgB[128 * 32];
  f32x4 acc[4][4];
  #pragma unroll
  for (int i = 0; i < 4; i++)
    #pragma unroll
    for (int j = 0; j < 4; j++) acc[i][j] = (f32x4){0.f, 0.f, 0.f, 0.f};

  const int wm = (w & 1) * 64, wn = (w >> 1) * 64;
  const int lr = l & 15, lk = (l >> 4) * 8;

  for (int kt = 0; kt < K; kt += 32) {
    __syncthreads();
    #pragma unroll
    for (int j = 0; j < 2; j++) {
      const int c = j * 256 + t;                 // chunk id 0..511, 16B each
      gload16(A + (long)(m0 + (c >> 2)) * K + kt + (c & 3) * 8, (char*)lgA + c * 16);
      gload16(B + (long)(n0 + (c >> 2)) * K + kt + (c & 3) * 8, (char*)lgB + c * 16);
    }
    __syncthreads();
    bf16x8 af[4], bg[4];
    #pragma unroll
    for (int i = 0; i < 4; i++) {
      af[i] = *(const bf16x8*)&lgA[(wm + i * 16 + lr) * 32 + lk];
      bg[i] = *(const bf16x8*)&lgB[(wn + i * 16 + lr) * 32 + lk];
    }
    #pragma unroll
    for (int i = 0; i < 4; i++)
      #pragma unroll
      for (int j = 0; j < 4; j++)
        acc[i][j] = __builtin_amdgcn_mfma_f32_16x16x32_bf16(af[i], bg[j], acc[i][j], 0, 0, 0);
  }

  const int quad = l >> 4;
  #pragma unroll
  for (int i = 0; i < 4; i++) {
    const int mb = m0 + wm + i * 16 + quad * 4;
    #pragma unroll
    for (int j = 0; j < 4; j++) {
      const int n = n0 + wn + j * 16 + lr;
      float bia = 0.f;
      if (MODE == 3) { if (n < nmax) bia = bias[n]; } else { bia = bias[n]; }
      #pragma unroll
      for (int r = 0; r < 4; r++) {
        const long m = mb + r;
        const float v = acc[i][j][r] + bia;
        const long idx = m * (long)ldc + n;
        if (MODE == 0)      { F0[idx] = v; F1[idx] = v; }
        else if (MODE == 1) { U0[idx] = f2bf(tanhf(v)); }
        else if (MODE == 2) { F0[idx] = (1.f - GAMMA) * F0[idx] + GAMMA * (v + R0[idx]); }
        else                { if (n < nmax) F0[idx] = v; }
      }
    }
  }
}

// LayerNorm over rows of 1024 fp32 -> bf16 out. One 256-thread block per row.
__global__ __launch_bounds__(256)
void ln_bf16(const float* __restrict__ h, const float* __restrict__ gw,
             const float* __restrict__ gb, unsigned short* __restrict__ o)
{
  const int row = blockIdx.x, t = threadIdx.x;
  const float4 v = ((const float4*)(h + (long)row * 1024))[t];
  float s = v.x + v.y + v.z + v.w;
  float q = v.x * v.x + v.y * v.y + v.z * v.z + v.w * v.w;
  #pragma unroll
  for (int o2 = 32; o2 > 0; o2 >>= 1) { s += __shfl_xor(s, o2); q += __shfl_xor(q, o2); }
  __shared__ float rs[4], rq[4];
  if ((t & 63) == 0) { rs[t >> 6] = s; rq[t >> 6] = q; }
  __syncthreads();
  s = rs[0] + rs[1] + rs[2] + rs[3];
  q = rq[0] + rq[1] + rq[2] + rq[3];
  const float mu  = s * (1.f / 1024.f);
  const float inv = rsqrtf(q * (1.f / 1024.f) - mu * mu + 1e-5f);
  const float4 wv = ((const float4*)gw)[t];
  const float4 bv = ((const float4*)gb)[t];
  ushort4 u;
  u.x = f2bf((v.x - mu) * inv * wv.x + bv.x);
  u.y = f2bf((v.y - mu) * inv * wv.y + bv.y);
  u.z = f2bf((v.z - mu) * inv * wv.z + bv.z);
  u.w = f2bf((v.w - mu) * inv * wv.w + bv.w);
  ((ushort4*)(o + (long)row * 1024))[t] = u;
}

// f32 -> bf16 with zero padding: dst[r][c] = (r<src_rows && c<src_cols) ? src : 0
__global__ __launch_bounds__(256)
void cvt_pad(const float* __restrict__ src, unsigned short* __restrict__ dst,
             int src_rows, int src_cols, int dst_cols)
{
  const int r = blockIdx.y;
  const int c = blockIdx.x * 256 + threadIdx.x;
  if (c >= dst_cols) return;
  unsigned short v = 0;
  if (r < src_rows && c < src_cols) v = f2bf(src[(long)r * src_cols + c]);
  dst[(long)r * dst_cols + c] = v;
}

// h fp32 -> bf16, 4 elems/thread
__global__ __launch_bounds__(256)
void cvt_h(const float* __restrict__ h, unsigned short* __restrict__ o)
{
  const long i = (long)blockIdx.x * 256 + threadIdx.x;
  const float4 v = ((const float4*)h)[i];
  ushort4 u;
  u.x = f2bf(v.x); u.y = f2bf(v.y); u.z = f2bf(v.z); u.w = f2bf(v.w);
  ((ushort4*)o)[i] = u;
}

extern "C" void kernel_launch(void* const* d_in, const int* in_sizes, int n_in,
                              void* d_out, int out_size, void* d_ws, size_t ws_size,
                              hipStream_t stream)
{
  const float* x       = (const float*)d_in[0];
  const float* embed_w = (const float*)d_in[1];
  const float* embed_b = (const float*)d_in[2];
  const float* W1_w    = (const float*)d_in[3];
  const float* W1_b    = (const float*)d_in[4];
  const float* W2_w    = (const float*)d_in[5];
  const float* W2_b    = (const float*)d_in[6];
  const float* norm_w  = (const float*)d_in[7];
  const float* norm_b  = (const float*)d_in[8];
  const float* head_w  = (const float*)d_in[9];
  const float* head_b  = (const float*)d_in[10];
  (void)in_sizes; (void)n_in; (void)out_size; (void)ws_size;

  // Workspace layout (all 256B-aligned)
  char* ws = (char*)d_ws;
  unsigned short* W1b  = (unsigned short*)(ws);              //  8,388,608  W1 bf16   [4096][1024]
  unsigned short* W2b  = (unsigned short*)(ws + 8388608);    //  8,388,608  W2 bf16   [1024][4096]
  unsigned short* xb   = (unsigned short*)(ws + 16777216);   //  6,553,600  x bf16    [4096][800] (K-pad)
  unsigned short* ewb  = (unsigned short*)(ws + 23330816);   //  1,638,400  embW bf16 [1024][800] (K-pad)
  unsigned short* hwb  = (unsigned short*)(ws + 24969216);   //  2,097,152  headW bf16[1024][1024] (row-pad)
  float*          xemb = (float*)(ws + 27066368);            // 16,777,216  x_emb f32 [4096][1024]
  float*          h    = (float*)(ws + 43843584);            // 16,777,216  h f32     [4096][1024]
  unsigned short* hn   = (unsigned short*)(ws + 60620800);   //  8,388,608  ln(h) bf16[4096][1024]
  unsigned short* act  = (unsigned short*)(ws + 69009408);   // 33,554,432  ffn act   [4096][4096]
  unsigned short* hb   = (unsigned short*)(ws + 102563840);  //  8,388,608  h bf16    [4096][1024]
  // total 110,952,448 B

  // Weight / input conversions (fp32 -> bf16, with padding where needed)
  cvt_pad<<<dim3(4, 4096), 256, 0, stream>>>(W1_w, W1b, 4096, 1024, 1024);
  cvt_pad<<<dim3(16, 1024), 256, 0, stream>>>(W2_w, W2b, 1024, 4096, 4096);
  cvt_pad<<<dim3(4, 4096), 256, 0, stream>>>(x, xb, 4096, 784, 800);
  cvt_pad<<<dim3(4, 1024), 256, 0, stream>>>(embed_w, ewb, 1024, 784, 800);
  cvt_pad<<<dim3(4, 1024), 256, 0, stream>>>(head_w, hwb, 1000, 1024, 1024);

  // x_emb = x @ embed_w^T + embed_b ; h = x_emb
  gemm_bt<0><<<dim3(8, 32), 256, 0, stream>>>(xb, ewb, 800, embed_b, 1024, 1024,
                                              xemb, h, nullptr, nullptr);

  for (int s = 0; s < 30; s++) {
    ln_bf16<<<4096, 256, 0, stream>>>(h, norm_w, norm_b, hn);
    gemm_bt<1><<<dim3(32, 32), 256, 0, stream>>>(hn, W1b, 1024, W1_b, 4096, 4096,
                                                 nullptr, nullptr, act, nullptr);
    gemm_bt<2><<<dim3(8, 32), 256, 0, stream>>>(act, W2b, 4096, W2_b, 1024, 1024,
                                                h, nullptr, nullptr, xemb);
  }

  cvt_h<<<4096, 256, 0, stream>>>(h, hb);
  gemm_bt<3><<<dim3(8, 32), 256, 0, stream>>>(hb, hwb, 1024, head_b, 1000, 1000,
                                              (float*)d_out, nullptr, nullptr, nullptr);
}

// Round 2
// 4477.274 us; speedup vs baseline: 1.1889x; 1.1889x over previous
//
#include <hip/hip_runtime.h>
#include <math.h>

#define GAMMA 0.5f

typedef __bf16 bf16x8 __attribute__((ext_vector_type(8)));
typedef float  f32x4  __attribute__((ext_vector_type(4)));

__device__ __forceinline__ unsigned short f2bf(float f){
  union { float ff; unsigned u; } x; x.ff = f;
  return (unsigned short)((x.u + 0x7fffu + ((x.u >> 16) & 1u)) >> 16);
}

__device__ __forceinline__ float fast_tanh(float v){
  // tanh(v) = 1 - 2/(exp(2v)+1); exp->v_exp_f32, rcp->v_rcp_f32 (~1e-7 rel, fine for bf16)
  float e = __expf(v + v);
  return 1.f - 2.f * __builtin_amdgcn_rcpf(e + 1.f);
}

__device__ __forceinline__ void gload16(const void* g, void* l){
  __builtin_amdgcn_global_load_lds((const __attribute__((address_space(1))) void*)g,
                                   (__attribute__((address_space(3))) void*)l,
                                   16, 0, 0);
}

// XOR swizzle term for LDS chunk placement: depends on row bits [3:0] only.
__device__ __forceinline__ int swz(int row){ return (row ^ (row >> 2)) & 3; }

// C = A[M,K] * B[N,K]^T. Tile 128(M) x BN(N), BK=32, 256 threads = 4 waves.
// BN=128: waves 2x2 of 64x64 (acc 4x4). BN=64: waves 2x2 of 64x32 (acc 4x2).
// LDS chunks (16B = 8 bf16) placed at chunk*(16B) with kq XOR-swizzled so
// quad-strided ds_read_b128 is 2-way-conflict-free (free per m136).
// XCD region swizzle: bid%8 -> XCD; give each XCD a compact RMxRN tile region
// so resident blocks share strips inside the 4MiB per-XCD L2.
// MODE 0: F0[idx]=v; F1[idx]=v        MODE 1: U0[idx]=bf16(tanh(v))
// MODE 2: F0[idx]=.5*F0+.5*(v+R0)     MODE 3: if(n<nmax) F0[idx]=v
template<int MODE, int BN>
__global__ __launch_bounds__(256)
void gemm_bt(const unsigned short* __restrict__ A,
             const unsigned short* __restrict__ B,
             int K, const float* __restrict__ bias,
             int ldc, int nmax, int RM, int MR, int RN,
             float* __restrict__ F0, float* __restrict__ F1,
             unsigned short* __restrict__ U0,
             const float* __restrict__ R0)
{
  constexpr int JN = BN / 32;          // 4 for BN=128, 2 for BN=64
  const int bid = blockIdx.y * gridDim.x + blockIdx.x;
  const int xcd = bid & 7, kk = bid >> 3;
  const int m0 = ((xcd % MR) * RM + (kk % RM)) * 128;
  const int n0 = ((xcd / MR) * RN + (kk / RM)) * BN;

  const int t = threadIdx.x, w = t >> 6, l = t & 63;
  __shared__ __align__(16) unsigned short lgA[128 * 32];
  __shared__ __align__(16) unsigned short lgB[BN * 32];
  f32x4 acc[4][JN];
  #pragma unroll
  for (int i = 0; i < 4; i++)
    #pragma unroll
    for (int j = 0; j < JN; j++) acc[i][j] = (f32x4){0.f, 0.f, 0.f, 0.f};

  const int wm = (w & 1) * 64, wn = (w >> 1) * (BN / 2);
  const int lr = l & 15, quad = l >> 4;

  for (int kt = 0; kt < K; kt += 32) {
    __syncthreads();
    #pragma unroll
    for (int j = 0; j < 2; j++) {
      const int c = j * 256 + t, row = c >> 2;
      const int kq = (c & 3) ^ swz(row);
      gload16(A + (long)(m0 + row) * K + kt + kq * 8, (char*)lgA + c * 16);
    }
    #pragma unroll
    for (int j = 0; j < BN / 64; j++) {
      const int c = j * 256 + t, row = c >> 2;
      const int kq = (c & 3) ^ swz(row);
      gload16(B + (long)(n0 + row) * K + kt + kq * 8, (char*)lgB + c * 16);
    }
    __syncthreads();
    bf16x8 af[4], bg[JN];
    #pragma unroll
    for (int i = 0; i < 4; i++) {
      const int r = wm + i * 16 + lr;
      af[i] = *(const bf16x8*)&lgA[(r * 4 + (quad ^ swz(r))) * 8];
    }
    #pragma unroll
    for (int j = 0; j < JN; j++) {
      const int r = wn + j * 16 + lr;
      bg[j] = *(const bf16x8*)&lgB[(r * 4 + (quad ^ swz(r))) * 8];
    }
    #pragma unroll
    for (int i = 0; i < 4; i++)
      #pragma unroll
      for (int j = 0; j < JN; j++)
        acc[i][j] = __builtin_amdgcn_mfma_f32_16x16x32_bf16(af[i], bg[j], acc[i][j], 0, 0, 0);
  }

  #pragma unroll
  for (int i = 0; i < 4; i++) {
    const int mb = m0 + wm + i * 16 + quad * 4;
    #pragma unroll
    for (int j = 0; j < JN; j++) {
      const int n = n0 + wn + j * 16 + lr;
      float bia = 0.f;
      if (MODE == 3) { if (n < nmax) bia = bias[n]; } else { bia = bias[n]; }
      #pragma unroll
      for (int r = 0; r < 4; r++) {
        const long m = mb + r;
        const float v = acc[i][j][r] + bia;
        const long idx = m * (long)ldc + n;
        if (MODE == 0)      { F0[idx] = v; F1[idx] = v; }
        else if (MODE == 1) { U0[idx] = f2bf(fast_tanh(v)); }
        else if (MODE == 2) { F0[idx] = (1.f - GAMMA) * F0[idx] + GAMMA * (v + R0[idx]); }
        else                { if (n < nmax) F0[idx] = v; }
      }
    }
  }
}

// LayerNorm over rows of 1024 fp32 -> bf16 out. One 256-thread block per row.
__global__ __launch_bounds__(256)
void ln_bf16(const float* __restrict__ h, const float* __restrict__ gw,
             const float* __restrict__ gb, unsigned short* __restrict__ o)
{
  const int row = blockIdx.x, t = threadIdx.x;
  const float4 v = ((const float4*)(h + (long)row * 1024))[t];
  float s = v.x + v.y + v.z + v.w;
  float q = v.x * v.x + v.y * v.y + v.z * v.z + v.w * v.w;
  #pragma unroll
  for (int o2 = 32; o2 > 0; o2 >>= 1) { s += __shfl_xor(s, o2); q += __shfl_xor(q, o2); }
  __shared__ float rs[4], rq[4];
  if ((t & 63) == 0) { rs[t >> 6] = s; rq[t >> 6] = q; }
  __syncthreads();
  s = rs[0] + rs[1] + rs[2] + rs[3];
  q = rq[0] + rq[1] + rq[2] + rq[3];
  const float mu  = s * (1.f / 1024.f);
  const float inv = rsqrtf(q * (1.f / 1024.f) - mu * mu + 1e-5f);
  const float4 wv = ((const float4*)gw)[t];
  const float4 bv = ((const float4*)gb)[t];
  ushort4 u;
  u.x = f2bf((v.x - mu) * inv * wv.x + bv.x);
  u.y = f2bf((v.y - mu) * inv * wv.y + bv.y);
  u.z = f2bf((v.z - mu) * inv * wv.z + bv.z);
  u.w = f2bf((v.w - mu) * inv * wv.w + bv.w);
  ((ushort4*)(o + (long)row * 1024))[t] = u;
}

// f32 -> bf16 with zero padding
__global__ __launch_bounds__(256)
void cvt_pad(const float* __restrict__ src, unsigned short* __restrict__ dst,
             int src_rows, int src_cols, int dst_cols)
{
  const int r = blockIdx.y;
  const int c = blockIdx.x * 256 + threadIdx.x;
  if (c >= dst_cols) return;
  unsigned short v = 0;
  if (r < src_rows && c < src_cols) v = f2bf(src[(long)r * src_cols + c]);
  dst[(long)r * dst_cols + c] = v;
}

// h fp32 -> bf16, 4 elems/thread
__global__ __launch_bounds__(256)
void cvt_h(const float* __restrict__ h, unsigned short* __restrict__ o)
{
  const long i = (long)blockIdx.x * 256 + threadIdx.x;
  const float4 v = ((const float4*)h)[i];
  ushort4 u;
  u.x = f2bf(v.x); u.y = f2bf(v.y); u.z = f2bf(v.z); u.w = f2bf(v.w);
  ((ushort4*)o)[i] = u;
}

extern "C" void kernel_launch(void* const* d_in, const int* in_sizes, int n_in,
                              void* d_out, int out_size, void* d_ws, size_t ws_size,
                              hipStream_t stream)
{
  const float* x       = (const float*)d_in[0];
  const float* embed_w = (const float*)d_in[1];
  const float* embed_b = (const float*)d_in[2];
  const float* W1_w    = (const float*)d_in[3];
  const float* W1_b    = (const float*)d_in[4];
  const float* W2_w    = (const float*)d_in[5];
  const float* W2_b    = (const float*)d_in[6];
  const float* norm_w  = (const float*)d_in[7];
  const float* norm_b  = (const float*)d_in[8];
  const float* head_w  = (const float*)d_in[9];
  const float* head_b  = (const float*)d_in[10];
  (void)in_sizes; (void)n_in; (void)out_size; (void)ws_size;

  // Workspace layout (all 256B-aligned)
  char* ws = (char*)d_ws;
  unsigned short* W1b  = (unsigned short*)(ws);              //  8,388,608  W1 bf16   [4096][1024]
  unsigned short* W2b  = (unsigned short*)(ws + 8388608);    //  8,388,608  W2 bf16   [1024][4096]
  unsigned short* xb   = (unsigned short*)(ws + 16777216);   //  6,553,600  x bf16    [4096][800] (K-pad)
  unsigned short* ewb  = (unsigned short*)(ws + 23330816);   //  1,638,400  embW bf16 [1024][800] (K-pad)
  unsigned short* hwb  = (unsigned short*)(ws + 24969216);   //  2,097,152  headW bf16[1024][1024] (row-pad)
  float*          xemb = (float*)(ws + 27066368);            // 16,777,216  x_emb f32 [4096][1024]
  float*          h    = (float*)(ws + 43843584);            // 16,777,216  h f32     [4096][1024]
  unsigned short* hn   = (unsigned short*)(ws + 60620800);   //  8,388,608  ln(h) bf16[4096][1024]
  unsigned short* act  = (unsigned short*)(ws + 69009408);   // 33,554,432  ffn act   [4096][4096]
  unsigned short* hb   = (unsigned short*)(ws + 102563840);  //  8,388,608  h bf16    [4096][1024]
  // total 110,952,448 B

  cvt_pad<<<dim3(4, 4096), 256, 0, stream>>>(W1_w, W1b, 4096, 1024, 1024);
  cvt_pad<<<dim3(16, 1024), 256, 0, stream>>>(W2_w, W2b, 1024, 4096, 4096);
  cvt_pad<<<dim3(4, 4096), 256, 0, stream>>>(x, xb, 4096, 784, 800);
  cvt_pad<<<dim3(4, 1024), 256, 0, stream>>>(embed_w, ewb, 1024, 784, 800);
  cvt_pad<<<dim3(4, 1024), 256, 0, stream>>>(head_w, hwb, 1000, 1024, 1024);

  // x_emb = x @ embed_w^T + embed_b ; h = x_emb
  // grid tiles: GM=32, GN=8 -> regions 4(m)x2(n) of 8x4: RM=8, MR=4, RN=4
  gemm_bt<0, 128><<<dim3(8, 32), 256, 0, stream>>>(xb, ewb, 800, embed_b, 1024, 1024,
                                                   8, 4, 4, xemb, h, nullptr, nullptr);

  for (int s = 0; s < 30; s++) {
    ln_bf16<<<4096, 256, 0, stream>>>(h, norm_w, norm_b, hn);
    // GM=32, GN=32 -> regions 4x2 of 8x16: RM=8, MR=4, RN=16
    gemm_bt<1, 128><<<dim3(32, 32), 256, 0, stream>>>(hn, W1b, 1024, W1_b, 4096, 4096,
                                                      8, 4, 16, nullptr, nullptr, act, nullptr);
    // BN=64: GM=32, GN=16 -> regions 4x2 of 8x8: RM=8, MR=4, RN=8
    gemm_bt<2, 64><<<dim3(16, 32), 256, 0, stream>>>(act, W2b, 4096, W2_b, 1024, 1024,
                                                     8, 4, 8, h, nullptr, nullptr, xemb);
  }

  cvt_h<<<4096, 256, 0, stream>>>(h, hb);
  // GM=32, GN=8 -> RM=8, MR=4, RN=4
  gemm_bt<3, 128><<<dim3(8, 32), 256, 0, stream>>>(hb, hwb, 1024, head_b, 1000, 1000,
                                                   8, 4, 4, (float*)d_out, nullptr, nullptr, nullptr);
}